// Round 1
// baseline (24.458 us; speedup 1.0000x reference)
//
#include <hip/hip_runtime.h>

#define B_N 8192
#define R_N 256
#define A_N 64
#define NCHUNK 32
#define RPC (R_N / NCHUNK)  // 8 r-values per thread

// Prep: sort abcd along last dim, emit {a, 1/(b-a), d, 1/(d-c)} per (r,a).
__global__ __launch_bounds__(256) void prep_kernel(
    const float4* __restrict__ abcd, float4* __restrict__ params) {
  int t = blockIdx.x * 256 + threadIdx.x;  // t = r*A_N + a
  float4 v = abcd[t];
  // 5-comparator sorting network for 4 elements
  float lo01 = fminf(v.x, v.y), hi01 = fmaxf(v.x, v.y);
  float lo23 = fminf(v.z, v.w), hi23 = fmaxf(v.z, v.w);
  float s0 = fminf(lo01, lo23);
  float t1 = fmaxf(lo01, lo23);
  float t2 = fminf(hi01, hi23);
  float s3 = fmaxf(hi01, hi23);
  float s1 = fminf(t1, t2);
  float s2 = fmaxf(t1, t2);
  params[t] = make_float4(s0, 1.0f / (s1 - s0), s3, 1.0f / (s3 - s2));
}

// One inner step: membership update for dimension A_. Static index into xr[].
#define STEP(A_) do {                                   \
    float4 q = p[(A_)];                                 \
    float xa = xr[(A_)];                                \
    float rise = (xa - q.x) * q.y;                      \
    float fall = (q.z - xa) * q.w;                      \
    w *= fminf(fmaxf(fminf(rise, fall), 0.0f), 1.0f);   \
  } while (0)

// Group of 8 steps followed by a wave-uniform dead-wave exit.
#define GRP(G_)                                                      \
  STEP((G_)+0); STEP((G_)+1); STEP((G_)+2); STEP((G_)+3);            \
  STEP((G_)+4); STEP((G_)+5); STEP((G_)+6); STEP((G_)+7);            \
  if (!__any(w > 0.0f)) goto r_done;

__global__ __launch_bounds__(256) void main_kernel(
    const float* __restrict__ x, const float4* __restrict__ params,
    const float* __restrict__ rho, float2* __restrict__ partial) {
  const int k = blockIdx.x * 256 + threadIdx.x;
  const int chunk = blockIdx.y;

  // x row -> 64 VGPRs (statically indexed everywhere below)
  float xr[A_N];
  const float4* xrow = reinterpret_cast<const float4*>(x + (size_t)k * A_N);
#pragma unroll
  for (int i = 0; i < A_N / 4; ++i) {
    float4 v = xrow[i];
    xr[4*i+0] = v.x; xr[4*i+1] = v.y; xr[4*i+2] = v.z; xr[4*i+3] = v.w;
  }

  float num = 0.0f, den = 0.0f;
  const int r0 = chunk * RPC;
#pragma unroll 1
  for (int r = r0; r < r0 + RPC; ++r) {
    const float4* __restrict__ p = params + r * A_N;  // uniform -> s_load
    float w = 1.0f;
    {
      GRP(0) GRP(8) GRP(16) GRP(24) GRP(32) GRP(40) GRP(48) GRP(56)
    }
r_done:
    if (__any(w > 0.0f)) {  // rare path: some lane has nonzero weight
      const float* __restrict__ rr = rho + r * (A_N + 1);
      float z = rr[A_N];
#pragma unroll
      for (int a = 0; a < A_N; ++a) z = fmaf(xr[a], rr[a], z);
      num = fmaf(z, w, num);  // w==0 lanes contribute exactly 0
      den += w;
    }
  }
  partial[(size_t)chunk * B_N + k] = make_float2(num, den);
}

__global__ __launch_bounds__(256) void final_kernel(
    const float2* __restrict__ partial, float* __restrict__ out) {
  int k = blockIdx.x * 256 + threadIdx.x;
  float num = 0.0f, den = 0.0f;
#pragma unroll
  for (int c = 0; c < NCHUNK; ++c) {
    float2 v = partial[(size_t)c * B_N + k];
    num += v.x;
    den += v.y;
  }
  out[k] = num / (den + 1e-13f);
}

extern "C" void kernel_launch(void* const* d_in, const int* in_sizes, int n_in,
                              void* d_out, int out_size, void* d_ws, size_t ws_size,
                              hipStream_t stream) {
  const float* x = (const float*)d_in[0];
  const float4* abcd = (const float4*)d_in[1];
  const float* rho = (const float*)d_in[2];
  float* out = (float*)d_out;

  float4* params = (float4*)d_ws;                                   // 256 KB
  float2* partial = (float2*)((char*)d_ws + (size_t)R_N * A_N * 16); // 2 MB

  hipLaunchKernelGGL(prep_kernel, dim3(R_N * A_N / 256), dim3(256), 0, stream,
                     abcd, params);
  hipLaunchKernelGGL(main_kernel, dim3(B_N / 256, NCHUNK), dim3(256), 0, stream,
                     x, params, rho, partial);
  hipLaunchKernelGGL(final_kernel, dim3(B_N / 256), dim3(256), 0, stream,
                     partial, out);
}

// Round 2
// 16.119 us; speedup vs baseline: 1.5173x; 1.5173x over previous
//
#include <hip/hip_runtime.h>

#define B_N 8192
#define R_N 256
#define A_N 64
#define KB 8      // k-values per block
#define NREG 16   // dims whose (a,d) are held in registers per lane

// Lane r = threadIdx.x owns rule r. Block owns k-range [blockIdx.x*KB, +KB).
// Hot loop: x[k][dim] is wave-uniform (s_load); (a,d) in VGPRs; no LDS/VMEM.
// w > 0  <=>  for all dims: (x-a)*(d-x) > 0  (exact, since a<b<c<d a.s.)
__global__ __launch_bounds__(256) void fuzzy_kernel(
    const float* __restrict__ x, const float4* __restrict__ abcd,
    const float* __restrict__ rho, float* __restrict__ out) {
  __shared__ float accn[KB], accd[KB];
  const int tid = threadIdx.x;
  if (tid < KB) { accn[tid] = 0.0f; accd[tid] = 0.0f; }
  __syncthreads();

  const int r = tid;  // rule index for this lane

  // One-time: support interval (a,d) for dims 0..NREG-1 -> registers.
  float av[NREG], dv[NREG];
#pragma unroll
  for (int i = 0; i < NREG; ++i) {
    float4 v = abcd[r * A_N + i];
    av[i] = fminf(fminf(v.x, v.y), fminf(v.z, v.w));
    dv[i] = fmaxf(fmaxf(v.x, v.y), fmaxf(v.z, v.w));
  }

  const int k0 = blockIdx.x * KB;
#pragma unroll 1
  for (int kk = 0; kk < KB; ++kk) {
    const float* __restrict__ xr = x + (size_t)(k0 + kk) * A_N;  // uniform
    float xv[NREG];
#pragma unroll
    for (int i = 0; i < NREG; ++i) xv[i] = xr[i];  // uniform -> s_load

#define T(i) ((xv[i] - av[i]) * (dv[i] - xv[i]))
    // dims 0..7 (P(wave alive after 8) ~ 66%)
    float m0 = T(0), m1 = T(1), m2 = T(2), m3 = T(3);
    m0 = fminf(m0, T(4)); m1 = fminf(m1, T(5));
    m2 = fminf(m2, T(6)); m3 = fminf(m3, T(7));
    float mm = fminf(fminf(m0, m1), fminf(m2, m3));
    if (!__any(mm > 0.0f)) continue;
    // dims 8..11 (P alive ~ 13%)
    m0 = fminf(m0, T(8));  m1 = fminf(m1, T(9));
    m2 = fminf(m2, T(10)); m3 = fminf(m3, T(11));
    mm = fminf(fminf(m0, m1), fminf(m2, m3));
    if (!__any(mm > 0.0f)) continue;
    // dims 12..15 (P alive ~ 1.8%)
    m0 = fminf(m0, T(12)); m1 = fminf(m1, T(13));
    m2 = fminf(m2, T(14)); m3 = fminf(m3, T(15));
    mm = fminf(fminf(m0, m1), fminf(m2, m3));
    if (!__any(mm > 0.0f)) continue;
#undef T

    // Cold: dims 16..63, lazy loads, vote every 4 dims.
    int g = 4;
#pragma unroll 1
    for (; g < 16; ++g) {
#pragma unroll
      for (int j = 0; j < 4; ++j) {
        float4 v = abcd[r * A_N + g * 4 + j];
        float a = fminf(fminf(v.x, v.y), fminf(v.z, v.w));
        float d = fmaxf(fmaxf(v.x, v.y), fmaxf(v.z, v.w));
        float xx = xr[g * 4 + j];
        mm = fminf(mm, (xx - a) * (d - xx));
      }
      if (!__any(mm > 0.0f)) break;
    }
    if (g < 16) continue;  // wave died before dim 64

    // Ultra-cold: some lane has w > 0 for this k. Exact evaluation.
    float w = 1.0f;
#pragma unroll 1
    for (int i = 0; i < A_N; ++i) {
      float4 v = abcd[r * A_N + i];
      float lo01 = fminf(v.x, v.y), hi01 = fmaxf(v.x, v.y);
      float lo23 = fminf(v.z, v.w), hi23 = fmaxf(v.z, v.w);
      float a = fminf(lo01, lo23), d = fmaxf(hi01, hi23);
      float t1 = fmaxf(lo01, lo23), t2 = fminf(hi01, hi23);
      float b = fminf(t1, t2), c = fmaxf(t1, t2);
      float xx = xr[i];
      float rise = (xx - a) / (b - a);
      float fall = (d - xx) / (d - c);
      w *= fmaxf(fminf(fminf(rise, 1.0f), fall), 0.0f);
    }
    if (w > 0.0f) {
      const float* __restrict__ rr = rho + r * (A_N + 1);
      float z = rr[A_N];
#pragma unroll 1
      for (int i = 0; i < A_N; ++i) z = fmaf(xr[i], rr[i], z);
      atomicAdd(&accn[kk], z * w);
      atomicAdd(&accd[kk], w);
    }
  }

  __syncthreads();
  if (tid < KB) out[k0 + tid] = accn[tid] / (accd[tid] + 1e-13f);
}

extern "C" void kernel_launch(void* const* d_in, const int* in_sizes, int n_in,
                              void* d_out, int out_size, void* d_ws, size_t ws_size,
                              hipStream_t stream) {
  const float* x = (const float*)d_in[0];
  const float4* abcd = (const float4*)d_in[1];
  const float* rho = (const float*)d_in[2];
  float* out = (float*)d_out;

  hipLaunchKernelGGL(fuzzy_kernel, dim3(B_N / KB), dim3(256), 0, stream,
                     x, abcd, rho, out);
}